// Round 1
// baseline (139.487 us; speedup 1.0000x reference)
//
#include <hip/hip_runtime.h>

#define EMBD 264        // L1(256) + 8 psqt
#define NROWS 20481     // HALFKP+1
#define NR4   5121      // ceil(NROWS/4)
#define QS 5080.0f      // int8 scale: 127/0.025
#define INVQS (1.0f/5080.0f)

typedef short short8 __attribute__((ext_vector_type(8)));
typedef float f32x4  __attribute__((ext_vector_type(4)));

__device__ __forceinline__ float clamp01(float x) { return fminf(fmaxf(x, 0.f), 1.f); }
__device__ __forceinline__ unsigned short f2bf(float f) {
    unsigned u = __float_as_uint(f);
    u += 0x7fffu + ((u >> 16) & 1u);   // RNE
    return (unsigned short)(u >> 16);
}

// Merged prep: blocks [0, NR4) quantize emb -> emb8/psqt; blocks [NR4, NR4+256)
// build w1b (folded bf16 MFMA B-frags), b1c, w2p.
__global__ void prep_all(const float* __restrict__ emb, unsigned int* __restrict__ emb8,
                         float* __restrict__ psqt,
                         const float* __restrict__ w1, const float* __restrict__ fw1,
                         const float* __restrict__ b1, const float* __restrict__ fb1,
                         const float* __restrict__ w2,
                         unsigned short* __restrict__ w1b, float* __restrict__ b1c,
                         float* __restrict__ w2p) {
    if (blockIdx.x < NR4) {
        const int r = blockIdx.x * 4 + (threadIdx.x >> 6);
        const int t = threadIdx.x & 63;
        if (r >= NROWS) return;
        const bool pad = (r == NROWS - 1);
        const float4 v = *((const float4*)(emb + (size_t)r * EMBD) + t);
        int q0 = pad ? 128 : (int)rintf(v.x * QS) + 128;
        int q1 = pad ? 128 : (int)rintf(v.y * QS) + 128;
        int q2 = pad ? 128 : (int)rintf(v.z * QS) + 128;
        int q3 = pad ? 128 : (int)rintf(v.w * QS) + 128;
        q0 = min(max(q0, 0), 255); q1 = min(max(q1, 0), 255);
        q2 = min(max(q2, 0), 255); q3 = min(max(q3, 0), 255);
        emb8[(size_t)r * 64 + t] = (unsigned)q0 | ((unsigned)q1 << 8) |
                                   ((unsigned)q2 << 16) | ((unsigned)q3 << 24);
        if (t < 8) {
            float pv = emb[(size_t)r * EMBD + 256 + t];
            psqt[r * 8 + t] = pad ? 0.f : pv;
        }
    } else {
        const int e = (blockIdx.x - NR4) * 256 + threadIdx.x;   // 0..65535
        const int bkt = e >> 13, rem = e & 8191;
        const int s = rem >> 10, rem2 = rem & 1023;
        const int nt = rem2 >> 9, rem3 = rem2 & 511;
        const int ln = rem3 >> 3, j = rem3 & 7;
        const int n  = nt * 16 + (ln & 15);
        const int hi = ln >> 4;
        const int k  = s * 32 + hi * 8 + j;
        const float v = w1[(bkt * 32 + n) * 256 + k] + fw1[n * 256 + k];
        w1b[e] = f2bf(v);
        if (e < 256) b1c[e] = b1[e] + fb1[e & 31];
        if (e < 16384) {
            const int jr = e >> 6, i = e & 63;
            float x = 0.f;
            if (i < 31) x = w2[jr * 62 + i];
            else if (i >= 32 && i < 63) x = w2[jr * 62 + i - 1];
            w2p[e] = x;
        }
    }
}

__global__ __launch_bounds__(512, 4) void nnue_fwd_mfma(
    const unsigned int* __restrict__ emb8,    // (NROWS,64) dwords, biased u8
    const float* __restrict__ psqt,           // (NROWS,8) fp32
    const unsigned short* __restrict__ w1b,   // MFMA B frags, bf16
    const float* __restrict__ b1c,            // folded (256,)
    const float* __restrict__ w2p,            // padded (256,64)
    const float* __restrict__ b2,
    const float* __restrict__ wo,
    const float* __restrict__ bo,
    const float* __restrict__ us,
    const float* __restrict__ them,
    const int*   __restrict__ w_idx,
    const int*   __restrict__ b_idx,
    const int*   __restrict__ pcnt,
    float* __restrict__ out,
    int B)
{
    // 512 threads = 8 waves; 16 batch rows per block, 2 rows per wave.
    __shared__ unsigned short A_lds[16 * 280];          // 8960 B
    __shared__ float l1c[8 * 16 * 36];                  // 18432 B
    __shared__ float psq_lds[16];
    __shared__ int   bkt_lds[16];

    const int tid  = threadIdx.x;
    const int lane = tid & 63;
    const int w    = tid >> 6;            // wave 0..7

    // ---------- phase 1: gather (2 rows per wave) ----------
    // Deep-MLP version: all 64 feature-row loads for a batch row are issued
    // into explicit vw[32]/vb[32] arrays before any accumulation, so each
    // wave keeps ~64 loads in flight (L2/L3 latency fully covered).
    // __launch_bounds__(512,4) lifts the VGPR cap to ~128 to allow it.
    for (int rr = 0; rr < 2; ++rr) {
        const int m = w * 2 + rr;
        const int grow = __builtin_amdgcn_readfirstlane(blockIdx.x * 16 + m); // B%16==0

        const float usv = us[grow];
        const float thv = them[grow];
        int bucket = (pcnt[grow] - 1) >> 2;
        bucket = bucket > 7 ? 7 : bucket;
        bucket = __builtin_amdgcn_readfirstlane(bucket);

        const int* wrow = w_idx + grow * 32;   // wave-uniform pointers -> s_load
        const int* brow = b_idx + grow * 32;

        // psqt: per-lane scattered gather — issue early, reduce late so its
        // (long, multi-cacheline) latency hides under the bulk gather.
        const int kk = lane & 31;
        const int pidx = (lane < 32) ? wrow[kk] : brow[kk];
        float ps = psqt[pidx * 8 + bucket];

        const unsigned M = 0x00FF00FFu;
        const unsigned loff = (unsigned)(lane << 2);
        const char* ebase = (const char*)emb8;

        unsigned vw[32], vb[32];
#pragma unroll
        for (int k = 0; k < 32; ++k) {
            const unsigned iw = (unsigned)__builtin_amdgcn_readfirstlane(wrow[k]);
            vw[k] = *(const unsigned*)(ebase + (size_t)((iw << 8) + loff));
        }
#pragma unroll
        for (int k = 0; k < 32; ++k) {
            const unsigned ib = (unsigned)__builtin_amdgcn_readfirstlane(brow[k]);
            vb[k] = *(const unsigned*)(ebase + (size_t)((ib << 8) + loff));
        }

        // Packed u16 accumulate; 2 partial accumulators per stream to halve
        // the dependent-add chain.
        unsigned aw0a = 0, aw1a = 0, aw0b = 0, aw1b = 0;
#pragma unroll
        for (int k = 0; k < 32; k += 2) {
            aw0a += vw[k] & M;     aw1a += (vw[k] >> 8) & M;
            aw0b += vw[k+1] & M;   aw1b += (vw[k+1] >> 8) & M;
        }
        unsigned ab0a = 0, ab1a = 0, ab0b = 0, ab1b = 0;
#pragma unroll
        for (int k = 0; k < 32; k += 2) {
            ab0a += vb[k] & M;     ab1a += (vb[k] >> 8) & M;
            ab0b += vb[k+1] & M;   ab1b += (vb[k+1] >> 8) & M;
        }
        const unsigned aw0 = aw0a + aw0b, aw1 = aw1a + aw1b;
        const unsigned ab0 = ab0a + ab0b, ab1 = ab1a + ab1b;

        // psqt reduce (load issued long ago)
        ps += __shfl_xor(ps, 16);
        ps += __shfl_xor(ps, 8);
        ps += __shfl_xor(ps, 4);
        ps += __shfl_xor(ps, 2);
        ps += __shfl_xor(ps, 1);
        const float psq_w = __shfl(ps, 0);
        const float psq_b = __shfl(ps, 32);

        float4 aw4, ab4;
        aw4.x = ((int)(aw0 & 0xffffu) - 4096) * INVQS;
        aw4.y = ((int)(aw1 & 0xffffu) - 4096) * INVQS;
        aw4.z = ((int)(aw0 >> 16)     - 4096) * INVQS;
        aw4.w = ((int)(aw1 >> 16)     - 4096) * INVQS;
        ab4.x = ((int)(ab0 & 0xffffu) - 4096) * INVQS;
        ab4.y = ((int)(ab1 & 0xffffu) - 4096) * INVQS;
        ab4.z = ((int)(ab0 >> 16)     - 4096) * INVQS;
        ab4.w = ((int)(ab1 >> 16)     - 4096) * INVQS;

        float4 p, q;
        p.x = clamp01(usv * aw4.x + thv * ab4.x);
        p.y = clamp01(usv * aw4.y + thv * ab4.y);
        p.z = clamp01(usv * aw4.z + thv * ab4.z);
        p.w = clamp01(usv * aw4.w + thv * ab4.w);
        q.x = clamp01(usv * ab4.x + thv * aw4.x);
        q.y = clamp01(usv * ab4.y + thv * aw4.y);
        q.z = clamp01(usv * ab4.z + thv * aw4.z);
        q.w = clamp01(usv * ab4.w + thv * aw4.w);

        float4 po, qo;
        po.x = __shfl_xor(p.x, 32); po.y = __shfl_xor(p.y, 32);
        po.z = __shfl_xor(p.z, 32); po.w = __shfl_xor(p.w, 32);
        qo.x = __shfl_xor(q.x, 32); qo.y = __shfl_xor(q.y, 32);
        qo.z = __shfl_xor(q.z, 32); qo.w = __shfl_xor(q.w, 32);
        const float c127 = 127.f / 128.f;
        float4 l0f;
        if (lane < 32) {
            l0f.x = p.x * po.x * c127; l0f.y = p.y * po.y * c127;
            l0f.z = p.z * po.z * c127; l0f.w = p.w * po.w * c127;
        } else {
            l0f.x = q.x * qo.x * c127; l0f.y = q.y * qo.y * c127;
            l0f.z = q.z * qo.z * c127; l0f.w = q.w * qo.w * c127;
        }

        const unsigned lo  = (unsigned)f2bf(l0f.x) | ((unsigned)f2bf(l0f.y) << 16);
        const unsigned hi2 = (unsigned)f2bf(l0f.z) | ((unsigned)f2bf(l0f.w) << 16);
        *((unsigned long long*)&A_lds[m * 280 + lane * 4]) =
            ((unsigned long long)hi2 << 32) | (unsigned long long)lo;
        if (lane == 0) {
            psq_lds[m] = (psq_w - psq_b) * (usv - 0.5f);
            bkt_lds[m] = bucket;
        }
    }
    __syncthreads();

    // ---------- phase 2: l1 via MFMA, wave w handles bucket w ----------
    {
        const int col = lane & 15;
        const int hi  = lane >> 4;
        const int bkt = w;
        f32x4 acc[2];
        acc[0] = (f32x4){0.f, 0.f, 0.f, 0.f};
        acc[1] = (f32x4){0.f, 0.f, 0.f, 0.f};

#pragma unroll
        for (int s = 0; s < 8; ++s) {
            const short8 a = *((const short8*)&A_lds[col * 280 + s * 32 + hi * 8]);
#pragma unroll
            for (int nt = 0; nt < 2; ++nt) {
                const short8 bf = *((const short8*)&w1b[(((bkt * 8 + s) * 2 + nt) * 64 + lane) * 8]);
                acc[nt] = __builtin_amdgcn_mfma_f32_16x16x32_bf16(a, bf, acc[nt], 0, 0, 0);
            }
        }
#pragma unroll
        for (int nt = 0; nt < 2; ++nt) {
            const float bias = b1c[bkt * 32 + nt * 16 + col];
#pragma unroll
            for (int reg = 0; reg < 4; ++reg) {
                const int mr = hi * 4 + reg;
                l1c[(bkt * 16 + mr) * 36 + nt * 16 + col] = acc[nt][reg] + bias;
            }
        }
    }
    __syncthreads();

    // ---------- phase 3: l2 + l3, thread = (row, output-pair), tid < 256 ----------
    if (tid < 256) {
        const int row = tid >> 4;
        const int jj  = tid & 15;
        const int bkt = bkt_lds[row];
        const float4* crow = (const float4*)&l1c[(bkt * 16 + row) * 36];
        float4 c4[8];
#pragma unroll
        for (int b5 = 0; b5 < 8; ++b5) c4[b5] = crow[b5];

        const float4* wr0 = (const float4*)&w2p[(bkt * 32 + jj) * 64];
        const float4* wr1 = (const float4*)&w2p[(bkt * 32 + jj + 16) * 64];
        float acc0 = 0.f, acc1 = 0.f;
        const float kq = 255.f / 256.f;
#pragma unroll
        for (int b5 = 0; b5 < 8; ++b5) {
            const float4 cv = c4[b5];
            float4 sq, ln;
            sq.x = clamp01(cv.x * cv.x * kq); ln.x = clamp01(cv.x);
            sq.y = clamp01(cv.y * cv.y * kq); ln.y = clamp01(cv.y);
            sq.z = clamp01(cv.z * cv.z * kq); ln.z = clamp01(cv.z);
            sq.w = clamp01(cv.w * cv.w * kq); ln.w = clamp01(cv.w);
            const float4 ws0 = wr0[b5], wl0 = wr0[8 + b5];
            const float4 ws1 = wr1[b5], wl1 = wr1[8 + b5];
            acc0 += sq.x * ws0.x + sq.y * ws0.y + sq.z * ws0.z + sq.w * ws0.w;
            acc0 += ln.x * wl0.x + ln.y * wl0.y + ln.z * wl0.z + ln.w * wl0.w;
            acc1 += sq.x * ws1.x + sq.y * ws1.y + sq.z * ws1.z + sq.w * ws1.w;
            acc1 += ln.x * wl1.x + ln.y * wl1.y + ln.z * wl1.z + ln.w * wl1.w;
        }
        const float t0 = clamp01(acc0 + b2[bkt * 32 + jj])      * wo[bkt * 32 + jj];
        const float t1 = clamp01(acc1 + b2[bkt * 32 + jj + 16]) * wo[bkt * 32 + jj + 16];
        float t = t0 + t1;
        t += __shfl_xor(t, 8);
        t += __shfl_xor(t, 4);
        t += __shfl_xor(t, 2);
        t += __shfl_xor(t, 1);
        if (jj == 0) {
            out[blockIdx.x * 16 + row] = t + bo[bkt] + c4[7].w + psq_lds[row];
        }
    }
}

// ---------- fp32 fallback (self-contained, no workspace) ----------
__global__ __launch_bounds__(256) void nnue_fwd_f32(
    const float* __restrict__ emb,
    const float* __restrict__ w1e, const float* __restrict__ fw1,
    const float* __restrict__ b1e, const float* __restrict__ fb1,
    const float* __restrict__ w2,  const float* __restrict__ b2,
    const float* __restrict__ wo,  const float* __restrict__ bo,
    const float* __restrict__ us,  const float* __restrict__ them,
    const int* __restrict__ w_idx, const int* __restrict__ b_idx,
    const int* __restrict__ pcnt,  float* __restrict__ out, int B)
{
    const int lane = threadIdx.x & 63;
    const int row  = blockIdx.x * 4 + (threadIdx.x >> 6);
    if (row >= B) return;
    const float usv = us[row];
    const float thv = them[row];
    int bucket = (pcnt[row] - 1) >> 2;
    bucket = bucket > 7 ? 7 : bucket;
    bucket = __builtin_amdgcn_readfirstlane(bucket);
    const int kk = lane & 31;
    const int myidx = (lane < 32) ? w_idx[row * 32 + kk] : b_idx[row * 32 + kk];
    float ps = emb[(size_t)myidx * EMBD + 256 + bucket];
    ps += __shfl_xor(ps, 16); ps += __shfl_xor(ps, 8);
    ps += __shfl_xor(ps, 4);  ps += __shfl_xor(ps, 2); ps += __shfl_xor(ps, 1);
    const float psq_w = __shfl(ps, 0);
    const float psq_b = __shfl(ps, 32);
    float4 aw = make_float4(0,0,0,0), ab = make_float4(0,0,0,0);
#pragma unroll
    for (int k = 0; k < 32; ++k) {
        const int iw = __shfl(myidx, k);
        const int ib = __shfl(myidx, 32 + k);
        const float4 vw = *((const float4*)(emb + (size_t)iw * EMBD) + lane);
        const float4 vb = *((const float4*)(emb + (size_t)ib * EMBD) + lane);
        aw.x += vw.x; aw.y += vw.y; aw.z += vw.z; aw.w += vw.w;
        ab.x += vb.x; ab.y += vb.y; ab.z += vb.z; ab.w += vb.w;
    }
    float4 p, q;
    p.x = clamp01(usv*aw.x + thv*ab.x); p.y = clamp01(usv*aw.y + thv*ab.y);
    p.z = clamp01(usv*aw.z + thv*ab.z); p.w = clamp01(usv*aw.w + thv*ab.w);
    q.x = clamp01(usv*ab.x + thv*aw.x); q.y = clamp01(usv*ab.y + thv*aw.y);
    q.z = clamp01(usv*ab.z + thv*aw.z); q.w = clamp01(usv*ab.w + thv*aw.w);
    float4 po, qo;
    po.x = __shfl_xor(p.x,32); po.y = __shfl_xor(p.y,32);
    po.z = __shfl_xor(p.z,32); po.w = __shfl_xor(p.w,32);
    qo.x = __shfl_xor(q.x,32); qo.y = __shfl_xor(q.y,32);
    qo.z = __shfl_xor(q.z,32); qo.w = __shfl_xor(q.w,32);
    const float c127 = 127.f/128.f;
    float4 l0f;
    if (lane < 32) { l0f.x=p.x*po.x*c127; l0f.y=p.y*po.y*c127; l0f.z=p.z*po.z*c127; l0f.w=p.w*po.w*c127; }
    else           { l0f.x=q.x*qo.x*c127; l0f.y=q.y*qo.y*c127; l0f.z=q.z*qo.z*c127; l0f.w=q.w*qo.w*c127; }
    float part[32];
    const float4* w1p = (const float4*)(w1e + (size_t)bucket * 8192);
    const float4* f1p = (const float4*)fw1;
#pragma unroll
    for (int j = 0; j < 32; ++j) {
        float4 wv = w1p[j*64 + lane];
        float4 fv = f1p[j*64 + lane];
        wv.x+=fv.x; wv.y+=fv.y; wv.z+=fv.z; wv.w+=fv.w;
        part[j] = l0f.x*wv.x + l0f.y*wv.y + l0f.z*wv.z + l0f.w*wv.w;
    }
#pragma unroll
    for (int j = 0; j < 32; ++j) {
        float v = part[j];
        v += __shfl_xor(v,32); v += __shfl_xor(v,16); v += __shfl_xor(v,8);
        v += __shfl_xor(v,4);  v += __shfl_xor(v,2);  v += __shfl_xor(v,1);
        part[j] = v + b1e[bucket*32 + j] + fb1[j];
    }
    const float l1x_out = part[31];
    float acc2 = 0.f;
    if (lane < 32) {
        const float* w2r = w2 + (size_t)(bucket*32 + lane) * 62;
#pragma unroll
        for (int i = 0; i < 31; ++i) {
            const float a = part[i];
            acc2 += clamp01(a*a*(255.f/256.f)) * w2r[i];
            acc2 += clamp01(a) * w2r[31+i];
        }
        acc2 += b2[bucket*32 + lane];
        acc2 = clamp01(acc2) * wo[bucket*32 + lane];
    }
    acc2 += __shfl_xor(acc2,16); acc2 += __shfl_xor(acc2,8);
    acc2 += __shfl_xor(acc2,4);  acc2 += __shfl_xor(acc2,2); acc2 += __shfl_xor(acc2,1);
    if (lane == 0)
        out[row] = acc2 + bo[bucket] + l1x_out + (psq_w - psq_b) * (usv - 0.5f);
}

extern "C" void kernel_launch(void* const* d_in, const int* in_sizes, int n_in,
                              void* d_out, int out_size, void* d_ws, size_t ws_size,
                              hipStream_t stream) {
    const float* emb  = (const float*)d_in[0];
    const float* w1   = (const float*)d_in[1];
    const float* b1   = (const float*)d_in[2];
    const float* fw1  = (const float*)d_in[3];
    const float* fb1  = (const float*)d_in[4];
    const float* w2   = (const float*)d_in[5];
    const float* b2   = (const float*)d_in[6];
    const float* wo   = (const float*)d_in[7];
    const float* bo   = (const float*)d_in[8];
    const float* us   = (const float*)d_in[9];
    const float* them = (const float*)d_in[10];
    const int*   wi   = (const int*)d_in[11];
    const int*   bi   = (const int*)d_in[12];
    const int*   pc   = (const int*)d_in[13];
    float* out = (float*)d_out;

    const int B = in_sizes[9];               // 16384

    const size_t emb8_bytes = (size_t)NROWS * 256;   // 5,243,136
    const size_t psqt_bytes = (size_t)NROWS * 8 * 4; //   655,392
    const size_t w1b_bytes  = 65536 * 2;
    const size_t b1c_bytes  = 256 * 4;
    const size_t w2p_bytes  = 16384 * 4;
    const size_t need = emb8_bytes + psqt_bytes + w1b_bytes + b1c_bytes + w2p_bytes;

    if (ws_size >= need && (B % 16) == 0) {
        char* p = (char*)d_ws;
        unsigned int*   emb8 = (unsigned int*)p;     p += emb8_bytes;
        float*          psqt = (float*)p;            p += psqt_bytes;
        unsigned short* w1b  = (unsigned short*)p;   p += w1b_bytes;
        float*          b1c  = (float*)p;            p += b1c_bytes;
        float*          w2p  = (float*)p;

        prep_all<<<NR4 + 256, 256, 0, stream>>>(emb, emb8, psqt,
                                                w1, fw1, b1, fb1, w2, w1b, b1c, w2p);
        nnue_fwd_mfma<<<B / 16, 512, 0, stream>>>(emb8, psqt, w1b, b1c, w2p,
                                                  b2, wo, bo, us, them, wi, bi, pc, out, B);
    } else {
        nnue_fwd_f32<<<(B + 3) / 4, 256, 0, stream>>>(emb, w1, fw1, b1, fb1,
                                                      w2, b2, wo, bo, us, them, wi, bi, pc, out, B);
    }
}

// Round 2
// 139.052 us; speedup vs baseline: 1.0031x; 1.0031x over previous
//
#include <hip/hip_runtime.h>

#define EMBD 264        // L1(256) + 8 psqt
#define NROWS 20481     // HALFKP+1
#define NR4   5121      // ceil(NROWS/4)
#define QS 5080.0f      // int8 scale: 127/0.025
#define INVQS (1.0f/5080.0f)

typedef short short8 __attribute__((ext_vector_type(8)));
typedef float f32x4  __attribute__((ext_vector_type(4)));

__device__ __forceinline__ float clamp01(float x) { return fminf(fmaxf(x, 0.f), 1.f); }
__device__ __forceinline__ unsigned short f2bf(float f) {
    unsigned u = __float_as_uint(f);
    u += 0x7fffu + ((u >> 16) & 1u);   // RNE
    return (unsigned short)(u >> 16);
}

// Merged prep: blocks [0, NR4) quantize emb -> emb8/psqt; blocks [NR4, NR4+256)
// build w1b (folded bf16 MFMA B-frags), b1c, w2p.
__global__ void prep_all(const float* __restrict__ emb, unsigned int* __restrict__ emb8,
                         float* __restrict__ psqt,
                         const float* __restrict__ w1, const float* __restrict__ fw1,
                         const float* __restrict__ b1, const float* __restrict__ fb1,
                         const float* __restrict__ w2,
                         unsigned short* __restrict__ w1b, float* __restrict__ b1c,
                         float* __restrict__ w2p) {
    if (blockIdx.x < NR4) {
        const int r = blockIdx.x * 4 + (threadIdx.x >> 6);
        const int t = threadIdx.x & 63;
        if (r >= NROWS) return;
        const bool pad = (r == NROWS - 1);
        const float4 v = *((const float4*)(emb + (size_t)r * EMBD) + t);
        int q0 = pad ? 128 : (int)rintf(v.x * QS) + 128;
        int q1 = pad ? 128 : (int)rintf(v.y * QS) + 128;
        int q2 = pad ? 128 : (int)rintf(v.z * QS) + 128;
        int q3 = pad ? 128 : (int)rintf(v.w * QS) + 128;
        q0 = min(max(q0, 0), 255); q1 = min(max(q1, 0), 255);
        q2 = min(max(q2, 0), 255); q3 = min(max(q3, 0), 255);
        emb8[(size_t)r * 64 + t] = (unsigned)q0 | ((unsigned)q1 << 8) |
                                   ((unsigned)q2 << 16) | ((unsigned)q3 << 24);
        if (t < 8) {
            float pv = emb[(size_t)r * EMBD + 256 + t];
            psqt[r * 8 + t] = pad ? 0.f : pv;
        }
    } else {
        const int e = (blockIdx.x - NR4) * 256 + threadIdx.x;   // 0..65535
        const int bkt = e >> 13, rem = e & 8191;
        const int s = rem >> 10, rem2 = rem & 1023;
        const int nt = rem2 >> 9, rem3 = rem2 & 511;
        const int ln = rem3 >> 3, j = rem3 & 7;
        const int n  = nt * 16 + (ln & 15);
        const int hi = ln >> 4;
        const int k  = s * 32 + hi * 8 + j;
        const float v = w1[(bkt * 32 + n) * 256 + k] + fw1[n * 256 + k];
        w1b[e] = f2bf(v);
        if (e < 256) b1c[e] = b1[e] + fb1[e & 31];
        if (e < 16384) {
            const int jr = e >> 6, i = e & 63;
            float x = 0.f;
            if (i < 31) x = w2[jr * 62 + i];
            else if (i >= 32 && i < 63) x = w2[jr * 62 + i - 1];
            w2p[e] = x;
        }
    }
}

__global__ __launch_bounds__(512, 4) void nnue_fwd_mfma(
    const unsigned int* __restrict__ emb8,    // (NROWS,64) dwords, biased u8
    const float* __restrict__ psqt,           // (NROWS,8) fp32
    const unsigned short* __restrict__ w1b,   // MFMA B frags, bf16
    const float* __restrict__ b1c,            // folded (256,)
    const float* __restrict__ w2p,            // padded (256,64)
    const float* __restrict__ b2,
    const float* __restrict__ wo,
    const float* __restrict__ bo,
    const float* __restrict__ us,
    const float* __restrict__ them,
    const int*   __restrict__ w_idx,
    const int*   __restrict__ b_idx,
    const int*   __restrict__ pcnt,
    float* __restrict__ out,
    int B)
{
    // 512 threads = 8 waves; 16 batch rows per block, 2 rows per wave.
    __shared__ unsigned short A_lds[16 * 280];          // 8960 B
    __shared__ float l1c[8 * 16 * 36];                  // 18432 B
    __shared__ float psq_lds[16];
    __shared__ int   bkt_lds[16];

    const int tid  = threadIdx.x;
    const int lane = tid & 63;
    const int w    = tid >> 6;            // wave 0..7

    // ---------- phase 1: gather (2 rows per wave) ----------
    // Forced-MLP version: the 64 feature-row gathers per batch row are issued
    // as inline-asm volatile loads (addr-calc folded into the asm), so the
    // compiler CANNOT re-batch them to save registers (round-1 lesson: plain C
    // arrays were rescheduled back to ~4-deep, VGPR stayed at 36).
    // Counted waits: vmcnt(32) -> accumulate w-side while b-side in flight.
    for (int rr = 0; rr < 2; ++rr) {
        const int m = w * 2 + rr;
        const int grow = __builtin_amdgcn_readfirstlane(blockIdx.x * 16 + m); // B%16==0

        const float usv = us[grow];
        const float thv = them[grow];
        int bucket = (pcnt[grow] - 1) >> 2;
        bucket = bucket > 7 ? 7 : bucket;
        bucket = __builtin_amdgcn_readfirstlane(bucket);

        const int* wrow = w_idx + grow * 32;   // wave-uniform pointers -> s_load
        const int* brow = b_idx + grow * 32;

        // psqt: per-lane scattered gather, issued FIRST (oldest in vmcnt queue)
        // so its latency hides under the 64 bulk gathers.
        const int kk = lane & 31;
        const int pidx = (lane < 32) ? wrow[kk] : brow[kk];
        float psv;
        {
            const unsigned voffp = ((unsigned)pidx << 5) + ((unsigned)bucket << 2);
            asm volatile("global_load_dword %0, %1, %2"
                         : "=v"(psv) : "v"(voffp), "s"(psqt));
        }

        const unsigned M = 0x00FF00FFu;
        const unsigned loff = (unsigned)(lane << 2);

        // 64 gathers, all in flight. Each asm: voffset = (idx<<8)+lane*4 folded
        // into the load (dest reg doubles as address reg -> 1 VGPR per load).
        unsigned vw[32], vb[32];
#pragma unroll
        for (int k = 0; k < 32; ++k) {
            const int iw = __builtin_amdgcn_readfirstlane(wrow[k]);
            asm volatile("v_lshl_add_u32 %0, %2, 8, %3\n\t"
                         "global_load_dword %0, %0, %1"
                         : "=&v"(vw[k]) : "s"(emb8), "s"(iw), "v"(loff));
        }
#pragma unroll
        for (int k = 0; k < 32; ++k) {
            const int ib = __builtin_amdgcn_readfirstlane(brow[k]);
            asm volatile("v_lshl_add_u32 %0, %2, 8, %3\n\t"
                         "global_load_dword %0, %0, %1"
                         : "=&v"(vb[k]) : "s"(emb8), "s"(ib), "v"(loff));
        }

        // outstanding = psv + 32 w + 32 b = 65 (HW throttles at vmcnt cap, ok).
        // vmcnt(32): the 32 b-loads may still be in flight; psv + all w done.
        asm volatile("s_waitcnt vmcnt(32)" ::: "memory");
        __builtin_amdgcn_sched_barrier(0);

        // Packed u16 accumulate of the w stream (2 partials per sub-word
        // stream to shorten the dependent-add chain).
        unsigned aw0a = 0, aw1a = 0, aw0b = 0, aw1b = 0;
#pragma unroll
        for (int k = 0; k < 32; k += 2) {
            aw0a += vw[k] & M;     aw1a += (vw[k] >> 8) & M;
            aw0b += vw[k+1] & M;   aw1b += (vw[k+1] >> 8) & M;
        }
        const unsigned aw0 = aw0a + aw0b, aw1 = aw1a + aw1b;

        asm volatile("s_waitcnt vmcnt(0)" ::: "memory");
        __builtin_amdgcn_sched_barrier(0);

        unsigned ab0a = 0, ab1a = 0, ab0b = 0, ab1b = 0;
#pragma unroll
        for (int k = 0; k < 32; k += 2) {
            ab0a += vb[k] & M;     ab1a += (vb[k] >> 8) & M;
            ab0b += vb[k+1] & M;   ab1b += (vb[k+1] >> 8) & M;
        }
        const unsigned ab0 = ab0a + ab0b, ab1 = ab1a + ab1b;

        // psqt reduce (psv loaded long ago, covered by vmcnt(0))
        float ps = psv;
        ps += __shfl_xor(ps, 16);
        ps += __shfl_xor(ps, 8);
        ps += __shfl_xor(ps, 4);
        ps += __shfl_xor(ps, 2);
        ps += __shfl_xor(ps, 1);
        const float psq_w = __shfl(ps, 0);
        const float psq_b = __shfl(ps, 32);

        float4 aw4, ab4;
        aw4.x = ((int)(aw0 & 0xffffu) - 4096) * INVQS;
        aw4.y = ((int)(aw1 & 0xffffu) - 4096) * INVQS;
        aw4.z = ((int)(aw0 >> 16)     - 4096) * INVQS;
        aw4.w = ((int)(aw1 >> 16)     - 4096) * INVQS;
        ab4.x = ((int)(ab0 & 0xffffu) - 4096) * INVQS;
        ab4.y = ((int)(ab1 & 0xffffu) - 4096) * INVQS;
        ab4.z = ((int)(ab0 >> 16)     - 4096) * INVQS;
        ab4.w = ((int)(ab1 >> 16)     - 4096) * INVQS;

        float4 p, q;
        p.x = clamp01(usv * aw4.x + thv * ab4.x);
        p.y = clamp01(usv * aw4.y + thv * ab4.y);
        p.z = clamp01(usv * aw4.z + thv * ab4.z);
        p.w = clamp01(usv * aw4.w + thv * ab4.w);
        q.x = clamp01(usv * ab4.x + thv * aw4.x);
        q.y = clamp01(usv * ab4.y + thv * aw4.y);
        q.z = clamp01(usv * ab4.z + thv * aw4.z);
        q.w = clamp01(usv * ab4.w + thv * aw4.w);

        float4 po, qo;
        po.x = __shfl_xor(p.x, 32); po.y = __shfl_xor(p.y, 32);
        po.z = __shfl_xor(p.z, 32); po.w = __shfl_xor(p.w, 32);
        qo.x = __shfl_xor(q.x, 32); qo.y = __shfl_xor(q.y, 32);
        qo.z = __shfl_xor(q.z, 32); qo.w = __shfl_xor(q.w, 32);
        const float c127 = 127.f / 128.f;
        float4 l0f;
        if (lane < 32) {
            l0f.x = p.x * po.x * c127; l0f.y = p.y * po.y * c127;
            l0f.z = p.z * po.z * c127; l0f.w = p.w * po.w * c127;
        } else {
            l0f.x = q.x * qo.x * c127; l0f.y = q.y * qo.y * c127;
            l0f.z = q.z * qo.z * c127; l0f.w = q.w * qo.w * c127;
        }

        const unsigned lo  = (unsigned)f2bf(l0f.x) | ((unsigned)f2bf(l0f.y) << 16);
        const unsigned hi2 = (unsigned)f2bf(l0f.z) | ((unsigned)f2bf(l0f.w) << 16);
        *((unsigned long long*)&A_lds[m * 280 + lane * 4]) =
            ((unsigned long long)hi2 << 32) | (unsigned long long)lo;
        if (lane == 0) {
            psq_lds[m] = (psq_w - psq_b) * (usv - 0.5f);
            bkt_lds[m] = bucket;
        }
        // Pin row rr's 64 live load-dests to die before row rr+1 allocates its
        // own 64 — prevents 128-deep liveness -> scratch spill.
        __builtin_amdgcn_sched_barrier(0);
    }
    __syncthreads();

    // ---------- phase 2: l1 via MFMA, wave w handles bucket w ----------
    {
        const int col = lane & 15;
        const int hi  = lane >> 4;
        const int bkt = w;
        f32x4 acc[2];
        acc[0] = (f32x4){0.f, 0.f, 0.f, 0.f};
        acc[1] = (f32x4){0.f, 0.f, 0.f, 0.f};

#pragma unroll
        for (int s = 0; s < 8; ++s) {
            const short8 a = *((const short8*)&A_lds[col * 280 + s * 32 + hi * 8]);
#pragma unroll
            for (int nt = 0; nt < 2; ++nt) {
                const short8 bf = *((const short8*)&w1b[(((bkt * 8 + s) * 2 + nt) * 64 + lane) * 8]);
                acc[nt] = __builtin_amdgcn_mfma_f32_16x16x32_bf16(a, bf, acc[nt], 0, 0, 0);
            }
        }
#pragma unroll
        for (int nt = 0; nt < 2; ++nt) {
            const float bias = b1c[bkt * 32 + nt * 16 + col];
#pragma unroll
            for (int reg = 0; reg < 4; ++reg) {
                const int mr = hi * 4 + reg;
                l1c[(bkt * 16 + mr) * 36 + nt * 16 + col] = acc[nt][reg] + bias;
            }
        }
    }
    __syncthreads();

    // ---------- phase 3: l2 + l3, thread = (row, output-pair), tid < 256 ----------
    if (tid < 256) {
        const int row = tid >> 4;
        const int jj  = tid & 15;
        const int bkt = bkt_lds[row];
        const float4* crow = (const float4*)&l1c[(bkt * 16 + row) * 36];
        float4 c4[8];
#pragma unroll
        for (int b5 = 0; b5 < 8; ++b5) c4[b5] = crow[b5];

        const float4* wr0 = (const float4*)&w2p[(bkt * 32 + jj) * 64];
        const float4* wr1 = (const float4*)&w2p[(bkt * 32 + jj + 16) * 64];
        float acc0 = 0.f, acc1 = 0.f;
        const float kq = 255.f / 256.f;
#pragma unroll
        for (int b5 = 0; b5 < 8; ++b5) {
            const float4 cv = c4[b5];
            float4 sq, ln;
            sq.x = clamp01(cv.x * cv.x * kq); ln.x = clamp01(cv.x);
            sq.y = clamp01(cv.y * cv.y * kq); ln.y = clamp01(cv.y);
            sq.z = clamp01(cv.z * cv.z * kq); ln.z = clamp01(cv.z);
            sq.w = clamp01(cv.w * cv.w * kq); ln.w = clamp01(cv.w);
            const float4 ws0 = wr0[b5], wl0 = wr0[8 + b5];
            const float4 ws1 = wr1[b5], wl1 = wr1[8 + b5];
            acc0 += sq.x * ws0.x + sq.y * ws0.y + sq.z * ws0.z + sq.w * ws0.w;
            acc0 += ln.x * wl0.x + ln.y * wl0.y + ln.z * wl0.z + ln.w * wl0.w;
            acc1 += sq.x * ws1.x + sq.y * ws1.y + sq.z * ws1.z + sq.w * ws1.w;
            acc1 += ln.x * wl1.x + ln.y * wl1.y + ln.z * wl1.z + ln.w * wl1.w;
        }
        const float t0 = clamp01(acc0 + b2[bkt * 32 + jj])      * wo[bkt * 32 + jj];
        const float t1 = clamp01(acc1 + b2[bkt * 32 + jj + 16]) * wo[bkt * 32 + jj + 16];
        float t = t0 + t1;
        t += __shfl_xor(t, 8);
        t += __shfl_xor(t, 4);
        t += __shfl_xor(t, 2);
        t += __shfl_xor(t, 1);
        if (jj == 0) {
            out[blockIdx.x * 16 + row] = t + bo[bkt] + c4[7].w + psq_lds[row];
        }
    }
}

// ---------- fp32 fallback (self-contained, no workspace) ----------
__global__ __launch_bounds__(256) void nnue_fwd_f32(
    const float* __restrict__ emb,
    const float* __restrict__ w1e, const float* __restrict__ fw1,
    const float* __restrict__ b1e, const float* __restrict__ fb1,
    const float* __restrict__ w2,  const float* __restrict__ b2,
    const float* __restrict__ wo,  const float* __restrict__ bo,
    const float* __restrict__ us,  const float* __restrict__ them,
    const int* __restrict__ w_idx, const int* __restrict__ b_idx,
    const int* __restrict__ pcnt,  float* __restrict__ out, int B)
{
    const int lane = threadIdx.x & 63;
    const int row  = blockIdx.x * 4 + (threadIdx.x >> 6);
    if (row >= B) return;
    const float usv = us[row];
    const float thv = them[row];
    int bucket = (pcnt[row] - 1) >> 2;
    bucket = bucket > 7 ? 7 : bucket;
    bucket = __builtin_amdgcn_readfirstlane(bucket);
    const int kk = lane & 31;
    const int myidx = (lane < 32) ? w_idx[row * 32 + kk] : b_idx[row * 32 + kk];
    float ps = emb[(size_t)myidx * EMBD + 256 + bucket];
    ps += __shfl_xor(ps, 16); ps += __shfl_xor(ps, 8);
    ps += __shfl_xor(ps, 4);  ps += __shfl_xor(ps, 2); ps += __shfl_xor(ps, 1);
    const float psq_w = __shfl(ps, 0);
    const float psq_b = __shfl(ps, 32);
    float4 aw = make_float4(0,0,0,0), ab = make_float4(0,0,0,0);
#pragma unroll
    for (int k = 0; k < 32; ++k) {
        const int iw = __shfl(myidx, k);
        const int ib = __shfl(myidx, 32 + k);
        const float4 vw = *((const float4*)(emb + (size_t)iw * EMBD) + lane);
        const float4 vb = *((const float4*)(emb + (size_t)ib * EMBD) + lane);
        aw.x += vw.x; aw.y += vw.y; aw.z += vw.z; aw.w += vw.w;
        ab.x += vb.x; ab.y += vb.y; ab.z += vb.z; ab.w += vb.w;
    }
    float4 p, q;
    p.x = clamp01(usv*aw.x + thv*ab.x); p.y = clamp01(usv*aw.y + thv*ab.y);
    p.z = clamp01(usv*aw.z + thv*ab.z); p.w = clamp01(usv*aw.w + thv*ab.w);
    q.x = clamp01(usv*ab.x + thv*aw.x); q.y = clamp01(usv*ab.y + thv*aw.y);
    q.z = clamp01(usv*ab.z + thv*aw.z); q.w = clamp01(usv*ab.w + thv*aw.w);
    float4 po, qo;
    po.x = __shfl_xor(p.x,32); po.y = __shfl_xor(p.y,32);
    po.z = __shfl_xor(p.z,32); po.w = __shfl_xor(p.w,32);
    qo.x = __shfl_xor(q.x,32); qo.y = __shfl_xor(q.y,32);
    qo.z = __shfl_xor(q.z,32); qo.w = __shfl_xor(q.w,32);
    const float c127 = 127.f/128.f;
    float4 l0f;
    if (lane < 32) { l0f.x=p.x*po.x*c127; l0f.y=p.y*po.y*c127; l0f.z=p.z*po.z*c127; l0f.w=p.w*po.w*c127; }
    else           { l0f.x=q.x*qo.x*c127; l0f.y=q.y*qo.y*c127; l0f.z=q.z*qo.z*c127; l0f.w=q.w*qo.w*c127; }
    float part[32];
    const float4* w1p = (const float4*)(w1e + (size_t)bucket * 8192);
    const float4* f1p = (const float4*)fw1;
#pragma unroll
    for (int j = 0; j < 32; ++j) {
        float4 wv = w1p[j*64 + lane];
        float4 fv = f1p[j*64 + lane];
        wv.x+=fv.x; wv.y+=fv.y; wv.z+=fv.z; wv.w+=fv.w;
        part[j] = l0f.x*wv.x + l0f.y*wv.y + l0f.z*wv.z + l0f.w*wv.w;
    }
#pragma unroll
    for (int j = 0; j < 32; ++j) {
        float v = part[j];
        v += __shfl_xor(v,32); v += __shfl_xor(v,16); v += __shfl_xor(v,8);
        v += __shfl_xor(v,4);  v += __shfl_xor(v,2);  v += __shfl_xor(v,1);
        part[j] = v + b1e[bucket*32 + j] + fb1[j];
    }
    const float l1x_out = part[31];
    float acc2 = 0.f;
    if (lane < 32) {
        const float* w2r = w2 + (size_t)(bucket*32 + lane) * 62;
#pragma unroll
        for (int i = 0; i < 31; ++i) {
            const float a = part[i];
            acc2 += clamp01(a*a*(255.f/256.f)) * w2r[i];
            acc2 += clamp01(a) * w2r[31+i];
        }
        acc2 += b2[bucket*32 + lane];
        acc2 = clamp01(acc2) * wo[bucket*32 + lane];
    }
    acc2 += __shfl_xor(acc2,16); acc2 += __shfl_xor(acc2,8);
    acc2 += __shfl_xor(acc2,4);  acc2 += __shfl_xor(acc2,2); acc2 += __shfl_xor(acc2,1);
    if (lane == 0)
        out[row] = acc2 + bo[bucket] + l1x_out + (psq_w - psq_b) * (usv - 0.5f);
}

extern "C" void kernel_launch(void* const* d_in, const int* in_sizes, int n_in,
                              void* d_out, int out_size, void* d_ws, size_t ws_size,
                              hipStream_t stream) {
    const float* emb  = (const float*)d_in[0];
    const float* w1   = (const float*)d_in[1];
    const float* b1   = (const float*)d_in[2];
    const float* fw1  = (const float*)d_in[3];
    const float* fb1  = (const float*)d_in[4];
    const float* w2   = (const float*)d_in[5];
    const float* b2   = (const float*)d_in[6];
    const float* wo   = (const float*)d_in[7];
    const float* bo   = (const float*)d_in[8];
    const float* us   = (const float*)d_in[9];
    const float* them = (const float*)d_in[10];
    const int*   wi   = (const int*)d_in[11];
    const int*   bi   = (const int*)d_in[12];
    const int*   pc   = (const int*)d_in[13];
    float* out = (float*)d_out;

    const int B = in_sizes[9];               // 16384

    const size_t emb8_bytes = (size_t)NROWS * 256;   // 5,243,136
    const size_t psqt_bytes = (size_t)NROWS * 8 * 4; //   655,392
    const size_t w1b_bytes  = 65536 * 2;
    const size_t b1c_bytes  = 256 * 4;
    const size_t w2p_bytes  = 16384 * 4;
    const size_t need = emb8_bytes + psqt_bytes + w1b_bytes + b1c_bytes + w2p_bytes;

    if (ws_size >= need && (B % 16) == 0) {
        char* p = (char*)d_ws;
        unsigned int*   emb8 = (unsigned int*)p;     p += emb8_bytes;
        float*          psqt = (float*)p;            p += psqt_bytes;
        unsigned short* w1b  = (unsigned short*)p;   p += w1b_bytes;
        float*          b1c  = (float*)p;            p += b1c_bytes;
        float*          w2p  = (float*)p;

        prep_all<<<NR4 + 256, 256, 0, stream>>>(emb, emb8, psqt,
                                                w1, fw1, b1, fb1, w2, w1b, b1c, w2p);
        nnue_fwd_mfma<<<B / 16, 512, 0, stream>>>(emb8, psqt, w1b, b1c, w2p,
                                                  b2, wo, bo, us, them, wi, bi, pc, out, B);
    } else {
        nnue_fwd_f32<<<(B + 3) / 4, 256, 0, stream>>>(emb, w1, fw1, b1, fb1,
                                                      w2, b2, wo, bo, us, them, wi, bi, pc, out, B);
    }
}

// Round 3
// 137.711 us; speedup vs baseline: 1.0129x; 1.0097x over previous
//
#include <hip/hip_runtime.h>

#define EMBD 264        // L1(256) + 8 psqt
#define NROWS 20481     // HALFKP+1
#define NR4   5121      // ceil(NROWS/4)
#define QS 5080.0f      // int8 scale: 127/0.025
#define INVQS (1.0f/5080.0f)

typedef short short8 __attribute__((ext_vector_type(8)));
typedef float f32x4  __attribute__((ext_vector_type(4)));

__device__ __forceinline__ float clamp01(float x) { return fminf(fmaxf(x, 0.f), 1.f); }
__device__ __forceinline__ unsigned short f2bf(float f) {
    unsigned u = __float_as_uint(f);
    u += 0x7fffu + ((u >> 16) & 1u);   // RNE
    return (unsigned short)(u >> 16);
}

// Merged prep: blocks [0, NR4) quantize emb -> emb8/psqt; blocks [NR4, NR4+256)
// build w1b (folded bf16 MFMA B-frags), b1c, w2p.
__global__ void prep_all(const float* __restrict__ emb, unsigned int* __restrict__ emb8,
                         float* __restrict__ psqt,
                         const float* __restrict__ w1, const float* __restrict__ fw1,
                         const float* __restrict__ b1, const float* __restrict__ fb1,
                         const float* __restrict__ w2,
                         unsigned short* __restrict__ w1b, float* __restrict__ b1c,
                         float* __restrict__ w2p) {
    if (blockIdx.x < NR4) {
        const int r = blockIdx.x * 4 + (threadIdx.x >> 6);
        const int t = threadIdx.x & 63;
        if (r >= NROWS) return;
        const bool pad = (r == NROWS - 1);
        const float4 v = *((const float4*)(emb + (size_t)r * EMBD) + t);
        int q0 = pad ? 128 : (int)rintf(v.x * QS) + 128;
        int q1 = pad ? 128 : (int)rintf(v.y * QS) + 128;
        int q2 = pad ? 128 : (int)rintf(v.z * QS) + 128;
        int q3 = pad ? 128 : (int)rintf(v.w * QS) + 128;
        q0 = min(max(q0, 0), 255); q1 = min(max(q1, 0), 255);
        q2 = min(max(q2, 0), 255); q3 = min(max(q3, 0), 255);
        emb8[(size_t)r * 64 + t] = (unsigned)q0 | ((unsigned)q1 << 8) |
                                   ((unsigned)q2 << 16) | ((unsigned)q3 << 24);
        if (t < 8) {
            float pv = emb[(size_t)r * EMBD + 256 + t];
            psqt[r * 8 + t] = pad ? 0.f : pv;
        }
    } else {
        const int e = (blockIdx.x - NR4) * 256 + threadIdx.x;   // 0..65535
        const int bkt = e >> 13, rem = e & 8191;
        const int s = rem >> 10, rem2 = rem & 1023;
        const int nt = rem2 >> 9, rem3 = rem2 & 511;
        const int ln = rem3 >> 3, j = rem3 & 7;
        const int n  = nt * 16 + (ln & 15);
        const int hi = ln >> 4;
        const int k  = s * 32 + hi * 8 + j;
        const float v = w1[(bkt * 32 + n) * 256 + k] + fw1[n * 256 + k];
        w1b[e] = f2bf(v);
        if (e < 256) b1c[e] = b1[e] + fb1[e & 31];
        if (e < 16384) {
            const int jr = e >> 6, i = e & 63;
            float x = 0.f;
            if (i < 31) x = w2[jr * 62 + i];
            else if (i >= 32 && i < 63) x = w2[jr * 62 + i - 1];
            w2p[e] = x;
        }
    }
}

__global__ __launch_bounds__(512, 4) void nnue_fwd_mfma(
    const unsigned int* __restrict__ emb8,    // (NROWS,64) dwords, biased u8
    const float* __restrict__ psqt,           // (NROWS,8) fp32
    const unsigned short* __restrict__ w1b,   // MFMA B frags, bf16
    const float* __restrict__ b1c,            // folded (256,)
    const float* __restrict__ w2p,            // padded (256,64)
    const float* __restrict__ b2,
    const float* __restrict__ wo,
    const float* __restrict__ bo,
    const float* __restrict__ us,
    const float* __restrict__ them,
    const int*   __restrict__ w_idx,
    const int*   __restrict__ b_idx,
    const int*   __restrict__ pcnt,
    float* __restrict__ out,
    int B)
{
    // 512 threads = 8 waves; 16 batch rows per block, 2 rows per wave.
    __shared__ unsigned short A_lds[16 * 280];          // 8960 B
    __shared__ float l1c[8 * 16 * 36];                  // 18432 B
    __shared__ float psq_lds[16];
    __shared__ int   bkt_lds[16];

    const int tid  = threadIdx.x;
    const int lane = tid & 63;
    const int w    = tid >> 6;            // wave 0..7

    // ---------- phase 1: gather (2 rows per wave) ----------
    // Wide-gather version: one global_load_dwordx4 fetches FOUR different
    // feature rows (4 groups of 16 lanes; 16 lanes x 16B = one 256B row).
    // 64 dword loads/row -> 16 dwordx4 loads/row: 3.6x fewer VMEM latency
    // quanta at unchanged bytes. Indices arrive in ONE coalesced vector load
    // and are distributed via __shfl (no more 64 scalar s_loads).
    const int t = lane & 15;              // position within a row (16B chunks)
    const int g = lane >> 4;              // group 0..3 (which row of a quad)
    const int d = (t << 2) + g;           // dword of the row this lane OWNS

    for (int rr = 0; rr < 2; ++rr) {
        const int m = w * 2 + rr;
        const int grow = __builtin_amdgcn_readfirstlane(blockIdx.x * 16 + m); // B%16==0

        const float usv = us[grow];
        const float thv = them[grow];
        int bucket = (pcnt[grow] - 1) >> 2;
        bucket = bucket > 7 ? 7 : bucket;
        bucket = __builtin_amdgcn_readfirstlane(bucket);

        const int* wrow = w_idx + grow * 32;
        const int* brow = b_idx + grow * 32;

        // One coalesced load: lanes 0..31 hold w indices, 32..63 hold b.
        const int kk = lane & 31;
        const int iv = (lane < 32) ? wrow[kk] : brow[kk];

        // psqt: per-lane scattered gather, issued early so its latency hides
        // under the bulk row gathers.
        float ps = psqt[(size_t)iv * 8 + bucket];

        // 16 quad-row gathers (8 w-side + 8 b-side).
        uint4 vws[8], vbs[8];
#pragma unroll
        for (int k = 0; k < 8; ++k) {
            const int rw = __shfl(iv, (k << 2) + g);
            vws[k] = *(const uint4*)((const char*)emb8 +
                                     (((unsigned)rw << 8) + (unsigned)(t << 4)));
        }
#pragma unroll
        for (int k = 0; k < 8; ++k) {
            const int rb = __shfl(iv, 32 + (k << 2) + g);
            vbs[k] = *(const uint4*)((const char*)emb8 +
                                     (((unsigned)rb << 8) + (unsigned)(t << 4)));
        }

        // Packed u16 accumulate, group-local (8 rows per group per side).
        const unsigned M = 0x00FF00FFu;
        unsigned a0w[4] = {0,0,0,0}, a1w[4] = {0,0,0,0};
        unsigned a0b[4] = {0,0,0,0}, a1b[4] = {0,0,0,0};
#pragma unroll
        for (int k = 0; k < 8; ++k) {
            a0w[0] += vws[k].x & M;  a1w[0] += (vws[k].x >> 8) & M;
            a0w[1] += vws[k].y & M;  a1w[1] += (vws[k].y >> 8) & M;
            a0w[2] += vws[k].z & M;  a1w[2] += (vws[k].z >> 8) & M;
            a0w[3] += vws[k].w & M;  a1w[3] += (vws[k].w >> 8) & M;
        }
#pragma unroll
        for (int k = 0; k < 8; ++k) {
            a0b[0] += vbs[k].x & M;  a1b[0] += (vbs[k].x >> 8) & M;
            a0b[1] += vbs[k].y & M;  a1b[1] += (vbs[k].y >> 8) & M;
            a0b[2] += vbs[k].z & M;  a1b[2] += (vbs[k].z >> 8) & M;
            a0b[3] += vbs[k].w & M;  a1b[3] += (vbs[k].w >> 8) & M;
        }

        // Cross-group reduce: sum the 4 groups (lanes t, t+16, t+32, t+48).
        // Max per u16 half: 32 rows * 255 = 8160 < 65536, no overflow.
#pragma unroll
        for (int j = 0; j < 4; ++j) {
            a0w[j] += __shfl_xor(a0w[j], 16);  a0w[j] += __shfl_xor(a0w[j], 32);
            a1w[j] += __shfl_xor(a1w[j], 16);  a1w[j] += __shfl_xor(a1w[j], 32);
            a0b[j] += __shfl_xor(a0b[j], 16);  a0b[j] += __shfl_xor(a0b[j], 32);
            a1b[j] += __shfl_xor(a1b[j], 16);  a1b[j] += __shfl_xor(a1b[j], 32);
        }
        // Each lane now owns dword d = 4t+g: select slot j = g.
        const bool gl = (g & 1) != 0, gh = (g & 2) != 0;
        const unsigned aw0 = gh ? (gl ? a0w[3] : a0w[2]) : (gl ? a0w[1] : a0w[0]);
        const unsigned aw1 = gh ? (gl ? a1w[3] : a1w[2]) : (gl ? a1w[1] : a1w[0]);
        const unsigned ab0 = gh ? (gl ? a0b[3] : a0b[2]) : (gl ? a0b[1] : a0b[0]);
        const unsigned ab1 = gh ? (gl ? a1b[3] : a1b[2]) : (gl ? a1b[1] : a1b[0]);

        // psqt reduce
        ps += __shfl_xor(ps, 16);
        ps += __shfl_xor(ps, 8);
        ps += __shfl_xor(ps, 4);
        ps += __shfl_xor(ps, 2);
        ps += __shfl_xor(ps, 1);
        const float psq_w = __shfl(ps, 0);
        const float psq_b = __shfl(ps, 32);

        // Lane's dword d packs features 4d..4d+3: (x,y,z,w) = (b0lo,b1lo,b0hi,b1hi)
        float4 aw4, ab4;
        aw4.x = ((int)(aw0 & 0xffffu) - 4096) * INVQS;
        aw4.y = ((int)(aw1 & 0xffffu) - 4096) * INVQS;
        aw4.z = ((int)(aw0 >> 16)     - 4096) * INVQS;
        aw4.w = ((int)(aw1 >> 16)     - 4096) * INVQS;
        ab4.x = ((int)(ab0 & 0xffffu) - 4096) * INVQS;
        ab4.y = ((int)(ab1 & 0xffffu) - 4096) * INVQS;
        ab4.z = ((int)(ab0 >> 16)     - 4096) * INVQS;
        ab4.w = ((int)(ab1 >> 16)     - 4096) * INVQS;

        float4 p, q;
        p.x = clamp01(usv * aw4.x + thv * ab4.x);
        p.y = clamp01(usv * aw4.y + thv * ab4.y);
        p.z = clamp01(usv * aw4.z + thv * ab4.z);
        p.w = clamp01(usv * aw4.w + thv * ab4.w);
        q.x = clamp01(usv * ab4.x + thv * aw4.x);
        q.y = clamp01(usv * ab4.y + thv * aw4.y);
        q.z = clamp01(usv * ab4.z + thv * aw4.z);
        q.w = clamp01(usv * ab4.w + thv * aw4.w);

        // Pairing: feature f partners f+128 = dword d+32 = lane xor 8.
        float4 po, qo;
        po.x = __shfl_xor(p.x, 8); po.y = __shfl_xor(p.y, 8);
        po.z = __shfl_xor(p.z, 8); po.w = __shfl_xor(p.w, 8);
        qo.x = __shfl_xor(q.x, 8); qo.y = __shfl_xor(q.y, 8);
        qo.z = __shfl_xor(q.z, 8); qo.w = __shfl_xor(q.w, 8);
        const float c127 = 127.f / 128.f;
        float4 l0f;
        if (t < 8) {   // d < 32: w-half products (A entries 4d..4d+3 in [0,128))
            l0f.x = p.x * po.x * c127; l0f.y = p.y * po.y * c127;
            l0f.z = p.z * po.z * c127; l0f.w = p.w * po.w * c127;
        } else {       // d >= 32: b-half products (entries in [128,256))
            l0f.x = q.x * qo.x * c127; l0f.y = q.y * qo.y * c127;
            l0f.z = q.z * qo.z * c127; l0f.w = q.w * qo.w * c127;
        }

        const unsigned lo  = (unsigned)f2bf(l0f.x) | ((unsigned)f2bf(l0f.y) << 16);
        const unsigned hi2 = (unsigned)f2bf(l0f.z) | ((unsigned)f2bf(l0f.w) << 16);
        *((unsigned long long*)&A_lds[m * 280 + d * 4]) =
            ((unsigned long long)hi2 << 32) | (unsigned long long)lo;
        if (lane == 0) {
            psq_lds[m] = (psq_w - psq_b) * (usv - 0.5f);
            bkt_lds[m] = bucket;
        }
    }
    __syncthreads();

    // ---------- phase 2: l1 via MFMA, wave w handles bucket w ----------
    {
        const int col = lane & 15;
        const int hi  = lane >> 4;
        const int bkt = w;
        f32x4 acc[2];
        acc[0] = (f32x4){0.f, 0.f, 0.f, 0.f};
        acc[1] = (f32x4){0.f, 0.f, 0.f, 0.f};

#pragma unroll
        for (int s = 0; s < 8; ++s) {
            const short8 a = *((const short8*)&A_lds[col * 280 + s * 32 + hi * 8]);
#pragma unroll
            for (int nt = 0; nt < 2; ++nt) {
                const short8 bf = *((const short8*)&w1b[(((bkt * 8 + s) * 2 + nt) * 64 + lane) * 8]);
                acc[nt] = __builtin_amdgcn_mfma_f32_16x16x32_bf16(a, bf, acc[nt], 0, 0, 0);
            }
        }
#pragma unroll
        for (int nt = 0; nt < 2; ++nt) {
            const float bias = b1c[bkt * 32 + nt * 16 + col];
#pragma unroll
            for (int reg = 0; reg < 4; ++reg) {
                const int mr = hi * 4 + reg;
                l1c[(bkt * 16 + mr) * 36 + nt * 16 + col] = acc[nt][reg] + bias;
            }
        }
    }
    __syncthreads();

    // ---------- phase 3: l2 + l3, thread = (row, output-pair), tid < 256 ----------
    if (tid < 256) {
        const int row = tid >> 4;
        const int jj  = tid & 15;
        const int bkt = bkt_lds[row];
        const float4* crow = (const float4*)&l1c[(bkt * 16 + row) * 36];
        float4 c4[8];
#pragma unroll
        for (int b5 = 0; b5 < 8; ++b5) c4[b5] = crow[b5];

        const float4* wr0 = (const float4*)&w2p[(bkt * 32 + jj) * 64];
        const float4* wr1 = (const float4*)&w2p[(bkt * 32 + jj + 16) * 64];
        float acc0 = 0.f, acc1 = 0.f;
        const float kq = 255.f / 256.f;
#pragma unroll
        for (int b5 = 0; b5 < 8; ++b5) {
            const float4 cv = c4[b5];
            float4 sq, ln;
            sq.x = clamp01(cv.x * cv.x * kq); ln.x = clamp01(cv.x);
            sq.y = clamp01(cv.y * cv.y * kq); ln.y = clamp01(cv.y);
            sq.z = clamp01(cv.z * cv.z * kq); ln.z = clamp01(cv.z);
            sq.w = clamp01(cv.w * cv.w * kq); ln.w = clamp01(cv.w);
            const float4 ws0 = wr0[b5], wl0 = wr0[8 + b5];
            const float4 ws1 = wr1[b5], wl1 = wr1[8 + b5];
            acc0 += sq.x * ws0.x + sq.y * ws0.y + sq.z * ws0.z + sq.w * ws0.w;
            acc0 += ln.x * wl0.x + ln.y * wl0.y + ln.z * wl0.z + ln.w * wl0.w;
            acc1 += sq.x * ws1.x + sq.y * ws1.y + sq.z * ws1.z + sq.w * ws1.w;
            acc1 += ln.x * wl1.x + ln.y * wl1.y + ln.z * wl1.z + ln.w * wl1.w;
        }
        const float t0 = clamp01(acc0 + b2[bkt * 32 + jj])      * wo[bkt * 32 + jj];
        const float t1 = clamp01(acc1 + b2[bkt * 32 + jj + 16]) * wo[bkt * 32 + jj + 16];
        float tsum = t0 + t1;
        tsum += __shfl_xor(tsum, 8);
        tsum += __shfl_xor(tsum, 4);
        tsum += __shfl_xor(tsum, 2);
        tsum += __shfl_xor(tsum, 1);
        if (jj == 0) {
            out[blockIdx.x * 16 + row] = tsum + bo[bkt] + c4[7].w + psq_lds[row];
        }
    }
}

// ---------- fp32 fallback (self-contained, no workspace) ----------
__global__ __launch_bounds__(256) void nnue_fwd_f32(
    const float* __restrict__ emb,
    const float* __restrict__ w1e, const float* __restrict__ fw1,
    const float* __restrict__ b1e, const float* __restrict__ fb1,
    const float* __restrict__ w2,  const float* __restrict__ b2,
    const float* __restrict__ wo,  const float* __restrict__ bo,
    const float* __restrict__ us,  const float* __restrict__ them,
    const int* __restrict__ w_idx, const int* __restrict__ b_idx,
    const int* __restrict__ pcnt,  float* __restrict__ out, int B)
{
    const int lane = threadIdx.x & 63;
    const int row  = blockIdx.x * 4 + (threadIdx.x >> 6);
    if (row >= B) return;
    const float usv = us[row];
    const float thv = them[row];
    int bucket = (pcnt[row] - 1) >> 2;
    bucket = bucket > 7 ? 7 : bucket;
    bucket = __builtin_amdgcn_readfirstlane(bucket);
    const int kk = lane & 31;
    const int myidx = (lane < 32) ? w_idx[row * 32 + kk] : b_idx[row * 32 + kk];
    float ps = emb[(size_t)myidx * EMBD + 256 + bucket];
    ps += __shfl_xor(ps, 16); ps += __shfl_xor(ps, 8);
    ps += __shfl_xor(ps, 4);  ps += __shfl_xor(ps, 2); ps += __shfl_xor(ps, 1);
    const float psq_w = __shfl(ps, 0);
    const float psq_b = __shfl(ps, 32);
    float4 aw = make_float4(0,0,0,0), ab = make_float4(0,0,0,0);
#pragma unroll
    for (int k = 0; k < 32; ++k) {
        const int iw = __shfl(myidx, k);
        const int ib = __shfl(myidx, 32 + k);
        const float4 vw = *((const float4*)(emb + (size_t)iw * EMBD) + lane);
        const float4 vb = *((const float4*)(emb + (size_t)ib * EMBD) + lane);
        aw.x += vw.x; aw.y += vw.y; aw.z += vw.z; aw.w += vw.w;
        ab.x += vb.x; ab.y += vb.y; ab.z += vb.z; ab.w += vb.w;
    }
    float4 p, q;
    p.x = clamp01(usv*aw.x + thv*ab.x); p.y = clamp01(usv*aw.y + thv*ab.y);
    p.z = clamp01(usv*aw.z + thv*ab.z); p.w = clamp01(usv*aw.w + thv*ab.w);
    q.x = clamp01(usv*ab.x + thv*aw.x); q.y = clamp01(usv*ab.y + thv*aw.y);
    q.z = clamp01(usv*ab.z + thv*aw.z); q.w = clamp01(usv*ab.w + thv*aw.w);
    float4 po, qo;
    po.x = __shfl_xor(p.x,32); po.y = __shfl_xor(p.y,32);
    po.z = __shfl_xor(p.z,32); po.w = __shfl_xor(p.w,32);
    qo.x = __shfl_xor(q.x,32); qo.y = __shfl_xor(q.y,32);
    qo.z = __shfl_xor(q.z,32); qo.w = __shfl_xor(q.w,32);
    const float c127 = 127.f/128.f;
    float4 l0f;
    if (lane < 32) { l0f.x=p.x*po.x*c127; l0f.y=p.y*po.y*c127; l0f.z=p.z*po.z*c127; l0f.w=p.w*po.w*c127; }
    else           { l0f.x=q.x*qo.x*c127; l0f.y=q.y*qo.y*c127; l0f.z=q.z*qo.z*c127; l0f.w=q.w*qo.w*c127; }
    float part[32];
    const float4* w1p = (const float4*)(w1e + (size_t)bucket * 8192);
    const float4* f1p = (const float4*)fw1;
#pragma unroll
    for (int j = 0; j < 32; ++j) {
        float4 wv = w1p[j*64 + lane];
        float4 fv = f1p[j*64 + lane];
        wv.x+=fv.x; wv.y+=fv.y; wv.z+=fv.z; wv.w+=fv.w;
        part[j] = l0f.x*wv.x + l0f.y*wv.y + l0f.z*wv.z + l0f.w*wv.w;
    }
#pragma unroll
    for (int j = 0; j < 32; ++j) {
        float v = part[j];
        v += __shfl_xor(v,32); v += __shfl_xor(v,16); v += __shfl_xor(v,8);
        v += __shfl_xor(v,4);  v += __shfl_xor(v,2);  v += __shfl_xor(v,1);
        part[j] = v + b1e[bucket*32 + j] + fb1[j];
    }
    const float l1x_out = part[31];
    float acc2 = 0.f;
    if (lane < 32) {
        const float* w2r = w2 + (size_t)(bucket*32 + lane) * 62;
#pragma unroll
        for (int i = 0; i < 31; ++i) {
            const float a = part[i];
            acc2 += clamp01(a*a*(255.f/256.f)) * w2r[i];
            acc2 += clamp01(a) * w2r[31+i];
        }
        acc2 += b2[bucket*32 + lane];
        acc2 = clamp01(acc2) * wo[bucket*32 + lane];
    }
    acc2 += __shfl_xor(acc2,16); acc2 += __shfl_xor(acc2,8);
    acc2 += __shfl_xor(acc2,4);  acc2 += __shfl_xor(acc2,2); acc2 += __shfl_xor(acc2,1);
    if (lane == 0)
        out[row] = acc2 + bo[bucket] + l1x_out + (psq_w - psq_b) * (usv - 0.5f);
}

extern "C" void kernel_launch(void* const* d_in, const int* in_sizes, int n_in,
                              void* d_out, int out_size, void* d_ws, size_t ws_size,
                              hipStream_t stream) {
    const float* emb  = (const float*)d_in[0];
    const float* w1   = (const float*)d_in[1];
    const float* b1   = (const float*)d_in[2];
    const float* fw1  = (const float*)d_in[3];
    const float* fb1  = (const float*)d_in[4];
    const float* w2   = (const float*)d_in[5];
    const float* b2   = (const float*)d_in[6];
    const float* wo   = (const float*)d_in[7];
    const float* bo   = (const float*)d_in[8];
    const float* us   = (const float*)d_in[9];
    const float* them = (const float*)d_in[10];
    const int*   wi   = (const int*)d_in[11];
    const int*   bi   = (const int*)d_in[12];
    const int*   pc   = (const int*)d_in[13];
    float* out = (float*)d_out;

    const int B = in_sizes[9];               // 16384

    const size_t emb8_bytes = (size_t)NROWS * 256;   // 5,243,136
    const size_t psqt_bytes = (size_t)NROWS * 8 * 4; //   655,392
    const size_t w1b_bytes  = 65536 * 2;
    const size_t b1c_bytes  = 256 * 4;
    const size_t w2p_bytes  = 16384 * 4;
    const size_t need = emb8_bytes + psqt_bytes + w1b_bytes + b1c_bytes + w2p_bytes;

    if (ws_size >= need && (B % 16) == 0) {
        char* p = (char*)d_ws;
        unsigned int*   emb8 = (unsigned int*)p;     p += emb8_bytes;
        float*          psqt = (float*)p;            p += psqt_bytes;
        unsigned short* w1b  = (unsigned short*)p;   p += w1b_bytes;
        float*          b1c  = (float*)p;            p += b1c_bytes;
        float*          w2p  = (float*)p;

        prep_all<<<NR4 + 256, 256, 0, stream>>>(emb, emb8, psqt,
                                                w1, fw1, b1, fb1, w2, w1b, b1c, w2p);
        nnue_fwd_mfma<<<B / 16, 512, 0, stream>>>(emb8, psqt, w1b, b1c, w2p,
                                                  b2, wo, bo, us, them, wi, bi, pc, out, B);
    } else {
        nnue_fwd_f32<<<(B + 3) / 4, 256, 0, stream>>>(emb, w1, fw1, b1, fb1,
                                                      w2, b2, wo, bo, us, them, wi, bi, pc, out, B);
    }
}